// Round 4
// baseline (288.237 us; speedup 1.0000x reference)
//
#include <hip/hip_runtime.h>
#include <hip/hip_bf16.h>

// WindowAttention3D: 3136 windows, N=64 tokens, C=128, H=4 heads, hd=32.
// One block per window, 4 waves, wave = head. x staged once in LDS (bf16);
// all inter-phase repacks via wave-private LDS. 3 barriers.
// R4: launch_bounds(256,3) for register headroom; softmax without max-subtract;
// row sums via ones-column MFMA; rpe+mask pre-combined into C-frag-order table.

typedef __bf16 bf16x8 __attribute__((ext_vector_type(8)));
typedef __bf16 bf16x4 __attribute__((ext_vector_type(4)));
typedef float f32x4 __attribute__((ext_vector_type(4)));

#define NWMASK 392
#define SCALE 0.17677669529663687f  // 1/sqrt(32)

// ---------------- prep: weights->bf16, rpe gather ----------------
__global__ void prep(const float* __restrict__ qkv_w, const float* __restrict__ proj_w,
                     const float* __restrict__ tbl, const int* __restrict__ ridx,
                     __bf16* __restrict__ wqkv, __bf16* __restrict__ wproj,
                     float* __restrict__ rpe) {
    int i = blockIdx.x * 256 + threadIdx.x;          // 81920 threads
    if (i < 49152) {
        wqkv[i] = (__bf16)qkv_w[i];                  // [384][128]
    } else if (i < 65536) {
        int j = i - 49152;  wproj[j] = (__bf16)proj_w[j];   // [128][128]
    } else {
        int j = i - 65536;                           // rpe [4][64][64]
        rpe[j] = tbl[ridx[j & 4095] * 4 + (j >> 12)];
    }
}

// ---------------- prep_cmb: combined (rpe+mask) bias in C-frag order ----------------
// cmb[w][h] is a 4096-float block: [mt][nt][lane][r], lane=(quad*16+l16),
// element = mask[w][row][col] + tbl[ridx[row][col]][h],
// row = mt*16+quad*4+r, col = nt*16+l16.  Coalesced writes; reads hit L2.
__global__ void prep_cmb(const float* __restrict__ mask, const float* __restrict__ tbl,
                         const int* __restrict__ ridx, float* __restrict__ cmb) {
    int t = blockIdx.x * 256 + threadIdx.x;          // 392*4*4096 = 6,422,528
    int w = t >> 14;
    int h = (t >> 12) & 3;
    int j = t & 4095;
    int mt = j >> 10, nt = (j >> 8) & 3, lane = (j >> 2) & 63, r = j & 3;
    int row = mt * 16 + (lane >> 4) * 4 + r;
    int col = nt * 16 + (lane & 15);
    cmb[t] = mask[w * 4096 + row * 64 + col] + tbl[ridx[row * 64 + col] * 4 + h];
}

// ---------------- main fused kernel ----------------
// LDS (bf16 el): [0,8704) xs [64][136] (overlay: osw 4x[64][34]);
//                [8704,18944) per-wave buf 2560 el: K stage -> Q stage -> V^T [32][72] -> P [16][72]
template<bool USE_CMB>
__global__ __launch_bounds__(256, 3) void wattn_main(
    const float* __restrict__ x, const float* __restrict__ mask,
    const float* __restrict__ qkv_b, const float* __restrict__ proj_b,
    const __bf16* __restrict__ wqkv, const __bf16* __restrict__ wproj,
    const float* __restrict__ rpe, const float* __restrict__ cmb,
    float* __restrict__ out)
{
    __shared__ __align__(16) __bf16 smem[18944];   // 37888 B
    const int win  = blockIdx.x;
    const int tid  = threadIdx.x;
    const int h    = tid >> 6;
    const int lane = tid & 63;
    const int quad = lane >> 4;
    const int l16  = lane & 15;

    __bf16* const xs  = smem;                     // [64][136]
    __bf16* const buf = smem + 8704 + h * 2560;   // wave-private
    __bf16* const osw = smem + h * 2176;          // O staging [64][34], overlays xs

    // ---- Phase 0: cooperative x staging, fp32 -> bf16, coalesced ----
    {
        const float* xb = x + (size_t)win * 8192;
        #pragma unroll
        for (int i = 0; i < 2; ++i) {
            const int row  = h * 16 + (lane >> 3) + i * 8;
            const int colg = (lane & 7) * 16;
            const float* xp = xb + row * 128 + colg;
            float4 a0 = *(const float4*)(xp);
            float4 a1 = *(const float4*)(xp + 4);
            float4 a2 = *(const float4*)(xp + 8);
            float4 a3 = *(const float4*)(xp + 12);
            bf16x8 t0, t1;
            t0[0]=(__bf16)a0.x; t0[1]=(__bf16)a0.y; t0[2]=(__bf16)a0.z; t0[3]=(__bf16)a0.w;
            t0[4]=(__bf16)a1.x; t0[5]=(__bf16)a1.y; t0[6]=(__bf16)a1.z; t0[7]=(__bf16)a1.w;
            t1[0]=(__bf16)a2.x; t1[1]=(__bf16)a2.y; t1[2]=(__bf16)a2.z; t1[3]=(__bf16)a2.w;
            t1[4]=(__bf16)a3.x; t1[5]=(__bf16)a3.y; t1[6]=(__bf16)a3.z; t1[7]=(__bf16)a3.w;
            *(bf16x8*)(xs + row * 136 + colg)     = t0;
            *(bf16x8*)(xs + row * 136 + colg + 8) = t1;
        }
    }
    __syncthreads();   // barrier 1: xs ready

    bf16x8 kf[4], qf[4], vf[2][2];

    // ---- K phase: feats 128+h*32+[0,32) -> buf [64][40] -> kf (B-frags) ----
    {
        bf16x8 wf[2][4]; float bb[2];
        #pragma unroll
        for (int nt = 0; nt < 2; ++nt) {
            const int ng = 128 + h * 32 + nt * 16 + l16;
            bb[nt] = qkv_b[ng];
            #pragma unroll
            for (int kt = 0; kt < 4; ++kt)
                wf[nt][kt] = *(const bf16x8*)(wqkv + ng * 128 + kt * 32 + quad * 8);
        }
        #pragma unroll
        for (int mt = 0; mt < 4; ++mt) {
            bf16x8 af[4];
            #pragma unroll
            for (int kt = 0; kt < 4; ++kt)
                af[kt] = *(const bf16x8*)(xs + (mt * 16 + l16) * 136 + kt * 32 + quad * 8);
            #pragma unroll
            for (int nt = 0; nt < 2; ++nt) {
                f32x4 acc = {0.f, 0.f, 0.f, 0.f};
                #pragma unroll
                for (int kt = 0; kt < 4; ++kt)
                    acc = __builtin_amdgcn_mfma_f32_16x16x32_bf16(af[kt], wf[nt][kt], acc, 0, 0, 0);
                #pragma unroll
                for (int r = 0; r < 4; ++r)
                    buf[(mt * 16 + quad * 4 + r) * 40 + nt * 16 + l16] = (__bf16)(acc[r] + bb[nt]);
            }
        }
        #pragma unroll
        for (int j = 0; j < 4; ++j)
            kf[j] = *(const bf16x8*)(buf + (j * 16 + l16) * 40 + quad * 8);
    }

    // ---- Q phase: feats h*32+[0,32), pre-scaled -> buf -> qf (A-frags) ----
    {
        bf16x8 wf[2][4]; float bb[2];
        #pragma unroll
        for (int nt = 0; nt < 2; ++nt) {
            const int ng = h * 32 + nt * 16 + l16;
            bb[nt] = qkv_b[ng];
            #pragma unroll
            for (int kt = 0; kt < 4; ++kt)
                wf[nt][kt] = *(const bf16x8*)(wqkv + ng * 128 + kt * 32 + quad * 8);
        }
        #pragma unroll
        for (int mt = 0; mt < 4; ++mt) {
            bf16x8 af[4];
            #pragma unroll
            for (int kt = 0; kt < 4; ++kt)
                af[kt] = *(const bf16x8*)(xs + (mt * 16 + l16) * 136 + kt * 32 + quad * 8);
            #pragma unroll
            for (int nt = 0; nt < 2; ++nt) {
                f32x4 acc = {0.f, 0.f, 0.f, 0.f};
                #pragma unroll
                for (int kt = 0; kt < 4; ++kt)
                    acc = __builtin_amdgcn_mfma_f32_16x16x32_bf16(af[kt], wf[nt][kt], acc, 0, 0, 0);
                #pragma unroll
                for (int r = 0; r < 4; ++r)
                    buf[(mt * 16 + quad * 4 + r) * 40 + nt * 16 + l16] = (__bf16)((acc[r] + bb[nt]) * SCALE);
            }
        }
        #pragma unroll
        for (int mt = 0; mt < 4; ++mt)
            qf[mt] = *(const bf16x8*)(buf + (mt * 16 + l16) * 40 + quad * 8);
    }

    // ---- V phase: feats 256+h*32+[0,32) -> buf as V^T [32][72] -> vf ----
    {
        bf16x8 wf[2][4]; float bb[2];
        #pragma unroll
        for (int nt = 0; nt < 2; ++nt) {
            const int ng = 256 + h * 32 + nt * 16 + l16;
            bb[nt] = qkv_b[ng];
            #pragma unroll
            for (int kt = 0; kt < 4; ++kt)
                wf[nt][kt] = *(const bf16x8*)(wqkv + ng * 128 + kt * 32 + quad * 8);
        }
        #pragma unroll
        for (int mt = 0; mt < 4; ++mt) {
            bf16x8 af[4];
            #pragma unroll
            for (int kt = 0; kt < 4; ++kt)
                af[kt] = *(const bf16x8*)(xs + (mt * 16 + l16) * 136 + kt * 32 + quad * 8);
            #pragma unroll
            for (int nt = 0; nt < 2; ++nt) {
                f32x4 acc = {0.f, 0.f, 0.f, 0.f};
                #pragma unroll
                for (int kt = 0; kt < 4; ++kt)
                    acc = __builtin_amdgcn_mfma_f32_16x16x32_bf16(af[kt], wf[nt][kt], acc, 0, 0, 0);
                bf16x4 pk;
                #pragma unroll
                for (int r = 0; r < 4; ++r) pk[r] = (__bf16)(acc[r] + bb[nt]);
                *(bf16x4*)(buf + (nt * 16 + l16) * 72 + mt * 16 + quad * 4) = pk;
            }
        }
        #pragma unroll
        for (int kt = 0; kt < 2; ++kt)
            #pragma unroll
            for (int nf = 0; nf < 2; ++nf)
                vf[kt][nf] = *(const bf16x8*)(buf + (nf * 16 + l16) * 72 + kt * 32 + quad * 8);
    }
    __syncthreads();   // barrier 2: xs reads done -> safe to overlay O staging

    // ---- attention: S -> exp (no max-subtract) -> P -> row-sum via ones-MFMA -> P@V ----
    const float* rpeh = rpe + h * 4096;
    const float* mw   = mask + (size_t)(win % NWMASK) * 4096;
    const float* cbh  = cmb + (((size_t)(win % NWMASK) * 4 + h) << 12);
    const __bf16 onev = (l16 == 0) ? (__bf16)1.0f : (__bf16)0.0f;
    const bf16x8 ones = {onev, onev, onev, onev, onev, onev, onev, onev};

    #pragma unroll
    for (int mt = 0; mt < 4; ++mt) {
        f32x4 sc[4];
        #pragma unroll
        for (int nt = 0; nt < 4; ++nt) {
            f32x4 z = {0.f, 0.f, 0.f, 0.f};
            sc[nt] = __builtin_amdgcn_mfma_f32_16x16x32_bf16(qf[mt], kf[nt], z, 0, 0, 0);
        }
        if (USE_CMB) {
            #pragma unroll
            for (int nt = 0; nt < 4; ++nt)
                sc[nt] += *(const f32x4*)(cbh + mt * 1024 + nt * 256 + lane * 4);
        } else {
            #pragma unroll
            for (int nt = 0; nt < 4; ++nt)
                #pragma unroll
                for (int r = 0; r < 4; ++r) {
                    const int row = mt * 16 + quad * 4 + r;
                    sc[nt][r] += rpeh[row * 64 + nt * 16 + l16] + mw[row * 64 + nt * 16 + l16];
                }
        }
        // exp + P staging (C-layout -> A-layout via wave-private buf)
        #pragma unroll
        for (int nt = 0; nt < 4; ++nt)
            #pragma unroll
            for (int r = 0; r < 4; ++r) {
                float e = __expf(sc[nt][r]);
                buf[(quad * 4 + r) * 72 + nt * 16 + l16] = (__bf16)e;
            }
        bf16x8 pf0 = *(const bf16x8*)(buf + l16 * 72 + quad * 8);
        bf16x8 pf1 = *(const bf16x8*)(buf + l16 * 72 + 32 + quad * 8);
        // row sums via ones-column MFMA (result in col 0 = lanes l16==0)
        f32x4 ss = {0.f, 0.f, 0.f, 0.f};
        ss = __builtin_amdgcn_mfma_f32_16x16x32_bf16(pf0, ones, ss, 0, 0, 0);
        ss = __builtin_amdgcn_mfma_f32_16x16x32_bf16(pf1, ones, ss, 0, 0, 0);
        f32x4 oa0 = {0.f, 0.f, 0.f, 0.f}, oa1 = {0.f, 0.f, 0.f, 0.f};
        oa0 = __builtin_amdgcn_mfma_f32_16x16x32_bf16(pf0, vf[0][0], oa0, 0, 0, 0);
        oa0 = __builtin_amdgcn_mfma_f32_16x16x32_bf16(pf1, vf[1][0], oa0, 0, 0, 0);
        oa1 = __builtin_amdgcn_mfma_f32_16x16x32_bf16(pf0, vf[0][1], oa1, 0, 0, 0);
        oa1 = __builtin_amdgcn_mfma_f32_16x16x32_bf16(pf1, vf[1][1], oa1, 0, 0, 0);
        #pragma unroll
        for (int r = 0; r < 4; ++r) {
            const float s  = __shfl(ss[r], lane & 48, 64);   // broadcast from col-0 lane of quad
            const float iv = 1.0f / s;
            osw[(mt * 16 + quad * 4 + r) * 34 + l16]      = (__bf16)(oa0[r] * iv);
            osw[(mt * 16 + quad * 4 + r) * 34 + 16 + l16] = (__bf16)(oa1[r] * iv);
        }
    }
    __syncthreads();   // barrier 3: O staging (all heads) ready

    // ---- proj GEMM: wave h = token band, K=128 over 4 heads' O ----
    bf16x8 of[4];
    #pragma unroll
    for (int kt = 0; kt < 4; ++kt)
        of[kt] = *(const bf16x8*)(smem + kt * 2176 + (h * 16 + l16) * 34 + quad * 8);
    #pragma unroll
    for (int nt = 0; nt < 8; ++nt) {
        const int ng = nt * 16 + l16;
        const float b = proj_b[ng];
        bf16x8 wf[4];
        #pragma unroll
        for (int kt = 0; kt < 4; ++kt)
            wf[kt] = *(const bf16x8*)(wproj + ng * 128 + kt * 32 + quad * 8);
        f32x4 acc = {0.f, 0.f, 0.f, 0.f};
        #pragma unroll
        for (int kt = 0; kt < 4; ++kt)
            acc = __builtin_amdgcn_mfma_f32_16x16x32_bf16(of[kt], wf[kt], acc, 0, 0, 0);
        float* dst = out + ((size_t)win * 64 + h * 16 + quad * 4) * 128 + ng;
        #pragma unroll
        for (int r = 0; r < 4; ++r) dst[(size_t)r * 128] = acc[r] + b;
    }
}

// ---------------- launch ----------------
extern "C" void kernel_launch(void* const* d_in, const int* in_sizes, int n_in,
                              void* d_out, int out_size, void* d_ws, size_t ws_size,
                              hipStream_t stream) {
    const float* x      = (const float*)d_in[0];
    const float* mask   = (const float*)d_in[1];
    const float* qkv_w  = (const float*)d_in[2];
    const float* qkv_b  = (const float*)d_in[3];
    const float* proj_w = (const float*)d_in[4];
    const float* proj_b = (const float*)d_in[5];
    const float* tbl    = (const float*)d_in[6];
    const int*   ridx   = (const int*)d_in[7];
    float* out = (float*)d_out;

    // ws: wqkv bf16 [49152] | wproj bf16 [16384] | rpe f32 [16384] | cmb f32 [392*4*4096]
    __bf16* wqkv  = (__bf16*)d_ws;
    __bf16* wproj = wqkv + 384 * 128;
    float*  rpe   = (float*)((char*)d_ws + 131072);
    float*  cmb   = (float*)((char*)d_ws + 196608);
    const size_t need_cmb = 196608 + (size_t)NWMASK * 4 * 4096 * 4;   // ~25.9 MB
    const bool use_cmb = ws_size >= need_cmb;

    prep<<<320, 256, 0, stream>>>(qkv_w, proj_w, tbl, ridx, wqkv, wproj, rpe);
    if (use_cmb) {
        prep_cmb<<<25088, 256, 0, stream>>>(mask, tbl, ridx, cmb);
        wattn_main<true><<<3136, 256, 0, stream>>>(x, mask, qkv_b, proj_b, wqkv, wproj, rpe, cmb, out);
    } else {
        wattn_main<false><<<3136, 256, 0, stream>>>(x, mask, qkv_b, proj_b, wqkv, wproj, rpe, cmb, out);
    }
}